// Round 7
// baseline (3984.672 us; speedup 1.0000x reference)
//
#include <hip/hip_runtime.h>

#define BB 64
#define TT 4096
#define HH 256
#define NTOK (BB * TT)

typedef _Float16 f16;
typedef _Float16 f16x2 __attribute__((ext_vector_type(2)));
typedef unsigned int uint;
typedef unsigned short ushort;
typedef uint uint4v __attribute__((ext_vector_type(4)));

__device__ __forceinline__ f16x2 u2h(uint u) { return __builtin_bit_cast(f16x2, u); }

__device__ __forceinline__ float fdot2(f16x2 a, f16x2 b, float c) {
    return __builtin_amdgcn_fdot2(a, b, c, false);
}

__device__ __forceinline__ uint pk_rtz(float a, float b) {  // v_cvt_pkrtz_f16_f32 -> uint
    auto p = __builtin_amdgcn_cvt_pkrtz(a, b);
    return __builtin_bit_cast(uint, p);
}

__device__ __forceinline__ float dpp_xor1(float v) {  // quad_perm [1,0,3,2]
    int t = __builtin_amdgcn_update_dpp(0, __builtin_bit_cast(int, v), 0xB1, 0xF, 0xF, true);
    return __builtin_bit_cast(float, t);
}
__device__ __forceinline__ float dpp_xor2(float v) {  // quad_perm [2,3,0,1]
    int t = __builtin_amdgcn_update_dpp(0, __builtin_bit_cast(int, v), 0x4E, 0xF, 0xF, true);
    return __builtin_bit_cast(float, t);
}
__device__ __forceinline__ float swz_xor4(float v) {  // ds_swizzle xor 4
    int t = __builtin_amdgcn_ds_swizzle(__builtin_bit_cast(int, v), 0x101F);
    return __builtin_bit_cast(float, t);
}
__device__ __forceinline__ float swz_xor8(float v) {  // ds_swizzle xor 8
    int t = __builtin_amdgcn_ds_swizzle(__builtin_bit_cast(int, v), 0x201F);
    return __builtin_bit_cast(float, t);
}

__device__ __forceinline__ uint packf16(float a, float b) {  // RNE pack (prep only)
    ushort lo = __builtin_bit_cast(ushort, (f16)a);
    ushort hi = __builtin_bit_cast(ushort, (f16)b);
    return (uint)lo | ((uint)hi << 16);
}

// ============ prep: W_hh -> per-thread register blocks (512-thread rnn) ============
// Thread tid: G=tid>>4 (rows 8G..8G+8), p=tid&15 (K-phase, cols [16p,16p+16)).
// Slot j (j<8) holds row 8G + (j ^ (p&7)); uint i (i<8) = cols 16p+2i, 16p+2i+1.
__global__ __launch_bounds__(256) void rnn_wswz_kernel(const float* __restrict__ Whh,
                                                       uint* __restrict__ Wsw) {
    int gid = blockIdx.x * 256 + threadIdx.x;  // 512*64 uints
    if (gid >= 512 * 64) return;
    int tid = gid >> 6, rem = gid & 63;
    int j = rem >> 3, i = rem & 7;
    int G = tid >> 4, p = tid & 15;
    int row = 8 * G + (j ^ (p & 7));
    int col = 16 * p + 2 * i;
    Wsw[gid] = packf16(Whh[row * 256 + col], Whh[row * 256 + col + 1]);
}

// ============ prep: MLP weights, pair-interleaved + bias-in-K ============
// Lane s owns k ≡ s (mod 4). Quarter = UQ uints: j<PJ: pair (k=8j+s, 8j+4+s);
// j==PJ: (bias, 0); j>PJ: 0.  Row = 4 quarters of UQ uints.
__global__ __launch_bounds__(256) void mlp_wpad_kernel(const float* __restrict__ W,
                                                       const float* __restrict__ bsrc,
                                                       uint* __restrict__ dst,
                                                       int N, int Kreal, int PJ, int UQ) {
    int gid = blockIdx.x * 256 + threadIdx.x;
    if (gid >= N * 4 * UQ) return;
    int n = gid / (4 * UQ);
    int rem = gid - n * 4 * UQ;
    int s = rem / UQ;
    int j = rem - s * UQ;
    uint val = 0;
    if (j < PJ) {
        int k0 = 8 * j + s, k1 = 8 * j + 4 + s;
        float f0 = (k0 < Kreal) ? W[n * Kreal + k0] : 0.f;
        float f1 = (k1 < Kreal) ? W[n * Kreal + k1] : 0.f;
        val = packf16(f0, f1);
    } else if (j == PJ) {
        val = packf16(bsrc[n], 0.f);
    }
    dst[gid] = val;
}

// ============ RNN: 64 blocks x 512 threads ============
// 16-way K-phase split (p=tid&15), 8 rows/thread, W in 64 VGPRs (pressure ~115
// -> fits 2 waves/EU at 128-reg budget; no AGPR shunt incentive).
// Butterfly: 4x dpp_xor1 + 2x dpp_xor2 + swz_xor4 + swz_xor8 (slot-permuted,
// cndmask-free). h ingest: 2 b128/thread. lgkm-only barrier; direct ht stores.
__global__ __launch_bounds__(512) __attribute__((amdgpu_waves_per_eu(2, 2))) void rnn_kernel(
        const float* __restrict__ x, const uint* __restrict__ Wsw,
        const float* __restrict__ Wih, const float* __restrict__ bih,
        const float* __restrict__ bhh, f16* __restrict__ ht, float* __restrict__ hlast) {
    const int b = blockIdx.x, tid = threadIdx.x;
    const int p = tid & 15, G = tid >> 4;
    const int jrow = 8 * G + (p & 7);
    __shared__ __align__(16) char hbuf[2][768];  // 16 phase-chunks x 48B
    __shared__ uint4 xs[2][128];                 // 64 rows x 32B, double-buffered

    uint4v wv[16];  // slot j = wv[2j], wv[2j+1]
    {
        const uint4v* wp = (const uint4v*)(Wsw + (size_t)tid * 64);
#pragma unroll
        for (int i = 0; i < 16; ++i) wv[i] = wp[i];
    }
#pragma unroll
    for (int i = 0; i < 16; ++i) asm volatile("" : "+v"(wv[i]));

    float wih[7];
#pragma unroll
    for (int i = 0; i < 7; ++i) wih[i] = Wih[jrow * 7 + i];
    const float bias = bih[jrow] + bhh[jrow];

    const float* xb = x + (size_t)b * TT * 12;
    uint4 xpre = make_uint4(0, 0, 0, 0);
    if (tid < 128) {
        int row = tid >> 1, u = tid & 1;
        xs[0][row * 2 + u] = *(const uint4*)(xb + row * 12 + u * 4);
        xpre = *(const uint4*)(xb + (64 + row) * 12 + u * 4);
    }
    if (tid < 192) ((uint*)hbuf[0])[tid] = 0;  // zero h0 buffer
    __syncthreads();

    const bool wlane = (p < 8);
    f16* htp = ht + (size_t)b * TT * 256 + (size_t)(64 * (jrow & 3) + (jrow >> 2));
    const int hoff = 48 * (jrow >> 4) + 2 * (jrow & 15);
    float hfin = 0.f;

#pragma unroll 2
    for (int t = 0; t < TT; ++t) {
        const int cur = t & 1;
        const int tile = (t >> 6) & 1, tstep = t & 63;

        // x contribution (wave-uniform broadcast reads)
        const float4 xa = ((const float4*)xs[tile])[tstep * 2];
        const float4 xc = ((const float4*)xs[tile])[tstep * 2 + 1];
        float xw = fmaf(xa.x, wih[0], bias);
        xw = fmaf(xa.y, wih[1], xw);
        xw = fmaf(xa.z, wih[2], xw);
        xw = fmaf(xa.w, wih[3], xw);
        xw = fmaf(xc.x, wih[4], xw);
        xw = fmaf(xc.y, wih[5], xw);
        xw = fmaf(xc.z, wih[6], xw);

        // this lane's K-phase of h (16 f16 = 2 b128), 48B-padded chunks
        uint4 h0 = *(const uint4*)(hbuf[cur] + p * 48);
        uint4 h1 = *(const uint4*)(hbuf[cur] + p * 48 + 16);

        float acc[8];
#pragma unroll
        for (int j = 0; j < 8; ++j) {
            uint4v w0 = wv[2 * j], w1 = wv[2 * j + 1];
            float a = 0.f;
            a = fdot2(u2h(h0.x), u2h(w0.x), a);
            a = fdot2(u2h(h0.y), u2h(w0.y), a);
            a = fdot2(u2h(h0.z), u2h(w0.z), a);
            a = fdot2(u2h(h0.w), u2h(w0.w), a);
            a = fdot2(u2h(h1.x), u2h(w1.x), a);
            a = fdot2(u2h(h1.y), u2h(w1.y), a);
            a = fdot2(u2h(h1.z), u2h(w1.z), a);
            a = fdot2(u2h(h1.w), u2h(w1.w), a);
            acc[j] = a;
        }

        // slot-permuted butterfly: lane p ends with full sum for row 8G+(p&7)
        acc[0] += dpp_xor1(acc[1]);
        acc[2] += dpp_xor1(acc[3]);
        acc[4] += dpp_xor1(acc[5]);
        acc[6] += dpp_xor1(acc[7]);
        acc[0] += dpp_xor2(acc[2]);
        acc[4] += dpp_xor2(acc[6]);
        acc[0] += swz_xor4(acc[4]);
        acc[0] += swz_xor8(acc[0]);
        float pre = acc[0] + xw;

        // tanh(x) = 2/(1+e^-2x) - 1
        float e = __expf(-2.0f * pre);
        float r = __builtin_amdgcn_rcpf(1.0f + e);
        float h = fmaf(2.0f, r, -1.0f);

        f16 hf = (f16)h;
        if (wlane) {
            *(f16*)(hbuf[cur ^ 1] + hoff) = hf;   // ds_write_b16
            htp[(size_t)t * 256] = hf;            // permuted ht store (no wait)
            if (t == TT - 1) hfin = h;
        }

        if (tstep == 32 && tid < 128) {
            int row = tid >> 1, u = tid & 1;
            xs[tile ^ 1][row * 2 + u] = xpre;
            int nt = (t & ~63) + 128 + row;
            if (nt > TT - 1) nt = TT - 1;
            xpre = *(const uint4*)(xb + nt * 12 + u * 4);
        }
        // barrier WITHOUT vmcnt drain (ht stores stay in flight)
        asm volatile("s_waitcnt lgkmcnt(0)\n\ts_barrier" ::: "memory");
    }
    if (wlane) hlast[b * 256 + jrow] = hfin;
}

// ============ MLP: 2048 blocks x 256 threads, 128 tokens/block (2/quad) ============
// Weights read DIRECTLY from global (L2-hot, broadcast-coalesced) — no LDS
// staging, no barriers. Lane s owns k ≡ s mod 4; z in regs (constant-indexed);
// new-z bounces through per-thread LDS slots (self-produce/self-consume only).
struct MlpP {
    const uint* w[7];
};

template <int UQ, int N>
__device__ __forceinline__ void mlp_layer(const uint* __restrict__ wg,
                                          const uint z0[36], const uint z1[36],
                                          uint* zb0, uint* zb1,
                                          int s, bool s1, bool s2) {
#pragma unroll 1
    for (int n8 = 0; n8 < N / 8; ++n8) {
        float va[8], vb[8];
#pragma unroll
        for (int u = 0; u < 8; ++u) {
            const uint4* wr = (const uint4*)(wg + (size_t)((n8 * 8 + u) * 4 + s) * UQ);
            float a = 0.f, b = 0.f;
#pragma unroll
            for (int jj = 0; jj < UQ / 4; ++jj) {
                uint4 wq = wr[jj];
                a = fdot2(u2h(z0[4 * jj + 0]), u2h(wq.x), a);
                a = fdot2(u2h(z0[4 * jj + 1]), u2h(wq.y), a);
                a = fdot2(u2h(z0[4 * jj + 2]), u2h(wq.z), a);
                a = fdot2(u2h(z0[4 * jj + 3]), u2h(wq.w), a);
                b = fdot2(u2h(z1[4 * jj + 0]), u2h(wq.x), b);
                b = fdot2(u2h(z1[4 * jj + 1]), u2h(wq.y), b);
                b = fdot2(u2h(z1[4 * jj + 2]), u2h(wq.z), b);
                b = fdot2(u2h(z1[4 * jj + 3]), u2h(wq.w), b);
            }
            a += dpp_xor1(a);
            a += dpp_xor2(a);  // full quad sum on all lanes
            b += dpp_xor1(b);
            b += dpp_xor2(b);
            va[u] = fmaxf(a, 0.01f * a);  // leaky relu
            vb[u] = fmaxf(b, 0.01f * b);
        }
        float alo = s2 ? (s1 ? va[3] : va[2]) : (s1 ? va[1] : va[0]);  // va[s]
        float ahi = s2 ? (s1 ? va[7] : va[6]) : (s1 ? va[5] : va[4]);  // va[s+4]
        float blo = s2 ? (s1 ? vb[3] : vb[2]) : (s1 ? vb[1] : vb[0]);
        float bhi = s2 ? (s1 ? vb[7] : vb[6]) : (s1 ? vb[5] : vb[4]);
        zb0[n8] = pk_rtz(alo, ahi);
        zb1[n8] = pk_rtz(blo, bhi);
    }
}

template <int CNT>
__device__ __forceinline__ void reload(uint* z, const uint* zb, uint bz) {
#pragma unroll
    for (int i = 0; i < CNT; ++i) z[i] = zb[i];
    z[CNT] = bz;
#pragma unroll
    for (int i = CNT + 1; i < 36; ++i) z[i] = 0;
}

__global__ __launch_bounds__(256) void mlp_kernel(const f16* __restrict__ ht,
                                                  const float* __restrict__ x,
                                                  MlpP mp, float* __restrict__ out) {
    __shared__ uint zbuf[256 * 66];  // 2 token-slots x 33 per thread; stride-66: 2-way (free)
    const int tid = threadIdx.x;
    const int s = tid & 3;
    const bool s1 = (s & 1) != 0, s2 = (s & 2) != 0;
    const size_t ta = (size_t)blockIdx.x * 128 + 2 * (tid >> 2);
    const size_t tb = ta + 1;
    uint* zb0 = zbuf + tid * 66;
    uint* zb1 = zb0 + 33;
    const uint bz = (s == 0) ? 0x00003C00u : 0u;  // f16 1.0 on lane 0

    uint z0[36], z1[36];
    {
        const uint4* hp = (const uint4*)(ht + ta * 256 + s * 64);
#pragma unroll
        for (int i = 0; i < 8; ++i) {
            uint4 v = hp[i];
            z0[4 * i + 0] = v.x;
            z0[4 * i + 1] = v.y;
            z0[4 * i + 2] = v.z;
            z0[4 * i + 3] = v.w;
        }
        const uint4* hq = (const uint4*)(ht + tb * 256 + s * 64);
#pragma unroll
        for (int i = 0; i < 8; ++i) {
            uint4 v = hq[i];
            z1[4 * i + 0] = v.x;
            z1[4 * i + 1] = v.y;
            z1[4 * i + 2] = v.z;
            z1[4 * i + 3] = v.w;
        }
        const float* xpa = x + ta * 12 + 7;
        const float* xpb = x + tb * 12 + 7;
        z0[32] = pk_rtz(xpa[s], (s == 0) ? xpa[4] : 0.f);
        z1[32] = pk_rtz(xpb[s], (s == 0) ? xpb[4] : 0.f);
        z0[33] = bz; z0[34] = 0; z0[35] = 0;
        z1[33] = bz; z1[34] = 0; z1[35] = 0;
    }

    mlp_layer<36, 256>(mp.w[0], z0, z1, zb0, zb1, s, s1, s2);
    reload<32>(z0, zb0, bz);
    reload<32>(z1, zb1, bz);
    mlp_layer<36, 128>(mp.w[1], z0, z1, zb0, zb1, s, s1, s2);
    reload<16>(z0, zb0, bz);
    reload<16>(z1, zb1, bz);
    mlp_layer<20, 64>(mp.w[2], z0, z1, zb0, zb1, s, s1, s2);
    reload<8>(z0, zb0, bz);
    reload<8>(z1, zb1, bz);
    mlp_layer<12, 32>(mp.w[3], z0, z1, zb0, zb1, s, s1, s2);
    reload<4>(z0, zb0, bz);
    reload<4>(z1, zb1, bz);
    mlp_layer<8, 16>(mp.w[4], z0, z1, zb0, zb1, s, s1, s2);
    reload<2>(z0, zb0, bz);
    reload<2>(z1, zb1, bz);
    mlp_layer<4, 8>(mp.w[5], z0, z1, zb0, zb1, s, s1, s2);
    reload<1>(z0, zb0, bz);
    reload<1>(z1, zb1, bz);

    // L7 head (N=7), bias in K, no activation
#pragma unroll
    for (int n = 0; n < 7; ++n) {
        const uint4 wq = *(const uint4*)(mp.w[6] + (size_t)(n * 4 + s) * 4);
        float a = 0.f, b = 0.f;
        a = fdot2(u2h(z0[0]), u2h(wq.x), a);
        a = fdot2(u2h(z0[1]), u2h(wq.y), a);
        a = fdot2(u2h(z0[2]), u2h(wq.z), a);
        a = fdot2(u2h(z0[3]), u2h(wq.w), a);
        b = fdot2(u2h(z1[0]), u2h(wq.x), b);
        b = fdot2(u2h(z1[1]), u2h(wq.y), b);
        b = fdot2(u2h(z1[2]), u2h(wq.z), b);
        b = fdot2(u2h(z1[3]), u2h(wq.w), b);
        a += dpp_xor1(a);
        a += dpp_xor2(a);
        b += dpp_xor1(b);
        b += dpp_xor2(b);
        if ((n & 3) == s) {
            out[ta * 7 + n] = a;
            out[tb * 7 + n] = b;
        }
    }
}

// ============ launch ============
extern "C" void kernel_launch(void* const* d_in, const int* in_sizes, int n_in,
                              void* d_out, int out_size, void* d_ws, size_t ws_size,
                              hipStream_t stream) {
    const float* x = (const float*)d_in[0];
    const float* Wih = (const float*)d_in[1];
    const float* Whh = (const float*)d_in[2];
    const float* bih = (const float*)d_in[3];
    const float* bhh = (const float*)d_in[4];
    const float* W[7];
    const float* bb[7];
    for (int j = 0; j < 7; ++j) {
        W[j] = (const float*)d_in[5 + 2 * j];
        bb[j] = (const float*)d_in[6 + 2 * j];
    }
    float* out = (float*)d_out;

    static const int Kd[7] = {261, 256, 128, 64, 32, 16, 8};
    static const int Nd[7] = {256, 128, 64, 32, 16, 8, 7};
    static const int PJd[7] = {33, 32, 16, 8, 4, 2, 1};
    static const int UQd[7] = {36, 36, 20, 12, 8, 4, 4};

    char* ws = (char*)d_ws;
    f16* ht = (f16*)ws;  // 128 MiB (permuted pair layout)
    size_t off = (size_t)NTOK * HH * 2;
    uint* Wsw = (uint*)(ws + off);
    off += (size_t)512 * 64 * 4;
    uint* wp[7];
    for (int j = 0; j < 7; ++j) {
        wp[j] = (uint*)(ws + off);
        off += (size_t)Nd[j] * 4 * UQd[j] * 4;
        off = (off + 15) & ~(size_t)15;
    }

    rnn_wswz_kernel<<<128, 256, 0, stream>>>(Whh, Wsw);
    for (int j = 0; j < 7; ++j) {
        int tot = Nd[j] * 4 * UQd[j];
        mlp_wpad_kernel<<<(tot + 255) / 256, 256, 0, stream>>>(W[j], bb[j], wp[j], Nd[j], Kd[j],
                                                               PJd[j], UQd[j]);
    }

    rnn_kernel<<<BB, 512, 0, stream>>>(x, Wsw, Wih, bih, bhh, ht, out + (size_t)NTOK * 7);

    MlpP mp;
    for (int j = 0; j < 7; ++j) mp.w[j] = wp[j];
    mlp_kernel<<<NTOK / 128, 256, 0, stream>>>(ht, x, mp, out);
}

// Round 8
// 1941.373 us; speedup vs baseline: 2.0525x; 2.0525x over previous
//
#include <hip/hip_runtime.h>

#define BB 64
#define TT 4096
#define HH 256
#define NTOK (BB * TT)

typedef _Float16 f16;
typedef _Float16 f16x2 __attribute__((ext_vector_type(2)));
typedef _Float16 f16x8 __attribute__((ext_vector_type(8)));
typedef float f32x4 __attribute__((ext_vector_type(4)));
typedef unsigned int uint;
typedef unsigned short ushort;
typedef uint uint4v __attribute__((ext_vector_type(4)));

__device__ __forceinline__ f16x2 u2h(uint u) { return __builtin_bit_cast(f16x2, u); }

__device__ __forceinline__ float fdot2(f16x2 a, f16x2 b, float c) {
    return __builtin_amdgcn_fdot2(a, b, c, false);
}

__device__ __forceinline__ float dpp_xor1(float v) {  // quad_perm [1,0,3,2]
    int t = __builtin_amdgcn_update_dpp(0, __builtin_bit_cast(int, v), 0xB1, 0xF, 0xF, true);
    return __builtin_bit_cast(float, t);
}
__device__ __forceinline__ float dpp_xor2(float v) {  // quad_perm [2,3,0,1]
    int t = __builtin_amdgcn_update_dpp(0, __builtin_bit_cast(int, v), 0x4E, 0xF, 0xF, true);
    return __builtin_bit_cast(float, t);
}

__device__ __forceinline__ uint packf16(float a, float b) {  // RNE pack (prep only)
    ushort lo = __builtin_bit_cast(ushort, (f16)a);
    ushort hi = __builtin_bit_cast(ushort, (f16)b);
    return (uint)lo | ((uint)hi << 16);
}

// ============ prep: W_hh -> per-thread register blocks ============
// RNN thread tid: qd=tid>>2, s=tid&3 (K-quarter, cols [64s,64s+64)).
// Slot q (q<4) holds row 4qd + (q^s); uint i (i<32) = cols 64s+2i, 64s+2i+1.
__global__ __launch_bounds__(256) void rnn_wswz_kernel(const float* __restrict__ Whh,
                                                       uint* __restrict__ Wsw) {
    int gid = blockIdx.x * 256 + threadIdx.x;  // 256*128 uints
    if (gid >= 256 * 128) return;
    int tid = gid >> 7, rem = gid & 127;
    int q = rem >> 5, i = rem & 31;
    int qd = tid >> 2, s = tid & 3;
    int row = 4 * qd + (q ^ s);
    int col = 64 * s + 2 * i;
    Wsw[gid] = packf16(Whh[row * 256 + col], Whh[row * 256 + col + 1]);
}

// ============ prep: MLP weights -> MFMA B-fragment-major layout ============
// frag (nt, ks): lane holds B[k=ks*32+(lane>>4)*8+j][n=nt*16+(lane&15)] = W[n][k..k+8],
// zero-padded for k>=Kreal or n>=N. dst[((nt*KS)+ks)*64 + lane] (uint4 = 8 f16).
__global__ __launch_bounds__(256) void bfrag_prep_kernel(const float* __restrict__ W,
                                                         uint4v* __restrict__ dst,
                                                         int N, int Kreal, int KS, int NT) {
    int gid = blockIdx.x * 256 + threadIdx.x;
    if (gid >= NT * KS * 64) return;
    int lane = gid & 63;
    int t = gid >> 6;
    int ks = t % KS, nt = t / KS;
    int n = nt * 16 + (lane & 15);
    int kb = ks * 32 + (lane >> 4) * 8;
    float f[8];
#pragma unroll
    for (int j = 0; j < 8; ++j) {
        int k = kb + j;
        f[j] = (n < N && k < Kreal) ? W[n * Kreal + k] : 0.f;
    }
    uint4v v;
    v.x = packf16(f[0], f[1]);
    v.y = packf16(f[2], f[3]);
    v.z = packf16(f[4], f[5]);
    v.w = packf16(f[6], f[7]);
    dst[gid] = v;
}

// ============ RNN: 64 blocks x 256 threads (R6 structure, known 1791 us) ============
// 4-way K-split (quads), 4 rows/thread, W in 128 regs. DPP-only reduce.
// ht stored PLAIN [b][t][j] (MFMA MLP consumes row-major).
__global__ __launch_bounds__(256) __attribute__((amdgpu_waves_per_eu(1, 1))) void rnn_kernel(
        const float* __restrict__ x, const uint* __restrict__ Wsw,
        const float* __restrict__ Wih, const float* __restrict__ bih,
        const float* __restrict__ bhh, f16* __restrict__ ht, float* __restrict__ hlast) {
    const int b = blockIdx.x, tid = threadIdx.x;
    const int s = tid & 3;
    __shared__ __align__(16) char hbuf[2][576];  // 4 quarters x 144B each
    __shared__ uint4 xs[2][128];                 // 64 rows x 32B, double-buffered

    uint4v wv[32];  // slot q = wv[q*8 .. q*8+7]
    {
        const uint4v* wp = (const uint4v*)(Wsw + (size_t)tid * 128);
#pragma unroll
        for (int i = 0; i < 32; ++i) wv[i] = wp[i];
    }
#pragma unroll
    for (int i = 0; i < 32; ++i) asm volatile("" : "+v"(wv[i]));

    float wih[7];
#pragma unroll
    for (int i = 0; i < 7; ++i) wih[i] = Wih[tid * 7 + i];
    const float bias = bih[tid] + bhh[tid];

    const float* xb = x + (size_t)b * TT * 12;
    uint4 xpre = make_uint4(0, 0, 0, 0);
    if (tid < 128) {
        int row = tid >> 1, u = tid & 1;
        xs[0][row * 2 + u] = *(const uint4*)(xb + row * 12 + u * 4);
        xpre = *(const uint4*)(xb + (64 + row) * 12 + u * 4);
    }
    if (tid < 144) ((uint*)hbuf[0])[tid] = 0;  // zero h0 (incl. pads)
    __syncthreads();

    f16* htp = ht + (size_t)b * TT * 256 + tid;  // PLAIN layout
    ushort hst[16];

    for (int tb = 0; tb < 256; ++tb) {
#pragma unroll
        for (int k = 0; k < 16; ++k) {
            const int t = tb * 16 + k;
            const int cur = k & 1;
            const int tile = (t >> 6) & 1, tstep = t & 63;

            // x contribution (wave-uniform broadcast reads)
            const float4 xa = ((const float4*)xs[tile])[tstep * 2];
            const float4 xc = ((const float4*)xs[tile])[tstep * 2 + 1];
            float xw = fmaf(xa.x, wih[0], bias);
            xw = fmaf(xa.y, wih[1], xw);
            xw = fmaf(xa.z, wih[2], xw);
            xw = fmaf(xa.w, wih[3], xw);
            xw = fmaf(xc.x, wih[4], xw);
            xw = fmaf(xc.y, wih[5], xw);
            xw = fmaf(xc.z, wih[6], xw);

            // this lane's K-quarter of h (64 f16), padded conflict-free layout
            const uint4* hq = (const uint4*)(hbuf[cur] + s * 144);
            uint hhv[32];
#pragma unroll
            for (int i = 0; i < 8; ++i) {
                uint4 v = hq[i];
                hhv[4 * i + 0] = v.x;
                hhv[4 * i + 1] = v.y;
                hhv[4 * i + 2] = v.z;
                hhv[4 * i + 3] = v.w;
            }

            float acc[4] = {0.f, 0.f, 0.f, 0.f};
#pragma unroll
            for (int q = 0; q < 4; ++q)
#pragma unroll
                for (int i = 0; i < 8; ++i) {
                    uint4v w = wv[q * 8 + i];
                    acc[q] = fdot2(u2h(hhv[4 * i + 0]), u2h(w.x), acc[q]);
                    acc[q] = fdot2(u2h(hhv[4 * i + 1]), u2h(w.y), acc[q]);
                    acc[q] = fdot2(u2h(hhv[4 * i + 2]), u2h(w.z), acc[q]);
                    acc[q] = fdot2(u2h(hhv[4 * i + 3]), u2h(w.w), acc[q]);
                }

            // slot-permuted butterfly: lane s ends with row 4qd+s == tid
            float uu = acc[0] + dpp_xor1(acc[1]);
            float vv = acc[2] + dpp_xor1(acc[3]);
            float pre = uu + dpp_xor2(vv) + xw;

            // tanh(x) = 2/(1+e^-2x) - 1
            float e = __expf(-2.0f * pre);
            float r = __builtin_amdgcn_rcpf(1.0f + e);
            float h = fmaf(2.0f, r, -1.0f);

            f16 hf = (f16)h;
            *(f16*)(hbuf[cur ^ 1] + (tid >> 6) * 144 + (tid & 63) * 2) = hf;
            hst[k] = __builtin_bit_cast(ushort, hf);
            if (k == 15 && tb == 255) hlast[b * 256 + tid] = h;

            if (tstep == 32 && tid < 128) {
                int row = tid >> 1, u = tid & 1;
                xs[tile ^ 1][row * 2 + u] = xpre;
                int nt = (t & ~63) + 128 + row;
                if (nt > TT - 1) nt = TT - 1;
                xpre = *(const uint4*)(xb + nt * 12 + u * 4);
            }
            asm volatile("s_waitcnt lgkmcnt(0)\n\ts_barrier" ::: "memory");
        }
        const size_t base = (size_t)(tb * 16) * 256;
#pragma unroll
        for (int k = 0; k < 16; ++k)
            htp[base + (size_t)k * 256] = __builtin_bit_cast(f16, hst[k]);
    }
}

// ============ MFMA MLP: 4096 blocks x 256 threads, 64 tokens/block ============
// mfma_f32_16x16x32_f16. A frag: z[m=lane&15][k=(lane>>4)*8+j] from LDS;
// B frag: pre-swizzled global (lane-contiguous, L2-hot); C: row=(lane>>4)*4+r,
// col=lane&15. z ping-pong in LDS (row stride 37 uint4 = 296 f16, conflict-free).
struct MlpB {
    const uint4v* bf[7];
    const float* bias[7];
};

template <int KS, int NT, bool MSPLIT>
__device__ __forceinline__ void mfma_layer(const uint4v* __restrict__ Bf,
                                           const float* __restrict__ bias, int Nreal,
                                           const uint4v* zin, uint4v* zout,
                                           int w, int lane, int m15, int q) {
    constexpr int NW = MSPLIT ? NT : (NT / 4);  // n-tiles per wave
    constexpr int MW = MSPLIT ? 1 : 4;          // m-tiles per wave
    const int ntb = MSPLIT ? 0 : w * NW;
    const int mtb = MSPLIT ? w : 0;
    f32x4 acc[MW][NW];
#pragma unroll
    for (int i = 0; i < MW; ++i)
#pragma unroll
        for (int j = 0; j < NW; ++j) acc[i][j] = (f32x4){0.f, 0.f, 0.f, 0.f};

#pragma unroll
    for (int ks = 0; ks < KS; ++ks) {
        f16x8 a[MW];
#pragma unroll
        for (int mt = 0; mt < MW; ++mt)
            a[mt] = __builtin_bit_cast(f16x8, zin[((mtb + mt) * 16 + m15) * 37 + ks * 4 + q]);
#pragma unroll
        for (int nt = 0; nt < NW; ++nt) {
            f16x8 b = __builtin_bit_cast(f16x8, Bf[((size_t)(ntb + nt) * KS + ks) * 64 + lane]);
#pragma unroll
            for (int mt = 0; mt < MW; ++mt)
                acc[mt][nt] =
                    __builtin_amdgcn_mfma_f32_16x16x32_f16(a[mt], b, acc[mt][nt], 0, 0, 0);
        }
    }
    f16* zo = (f16*)zout;
#pragma unroll
    for (int nt = 0; nt < NW; ++nt) {
        const int col = (ntb + nt) * 16 + m15;
        const float bv = (col < Nreal) ? bias[col] : 0.f;
#pragma unroll
        for (int mt = 0; mt < MW; ++mt) {
#pragma unroll
            for (int r = 0; r < 4; ++r) {
                float v = acc[mt][nt][r] + bv;
                v = fmaxf(v, 0.01f * v);  // leaky relu
                const int row = (mtb + mt) * 16 + q * 4 + r;
                zo[row * 296 + col] = (f16)v;
            }
        }
    }
}

__global__ __launch_bounds__(256) void mlp_kernel(const f16* __restrict__ ht,
                                                  const float* __restrict__ x,
                                                  MlpB P, float* __restrict__ out) {
    __shared__ uint4v z0[64 * 37];  // 37888 B each; ping-pong
    __shared__ uint4v z1[64 * 37];
    const int tid = threadIdx.x;
    const int w = tid >> 6, lane = tid & 63;
    const int m15 = lane & 15, q = lane >> 4;
    const int tok0 = blockIdx.x * 64;

    // stage z0 = [ht(256) | x_fixed(5) | 0-pad(27)] rows, 296-f16 stride
    for (int i = tid; i < 64 * 32; i += 256) {
        int r = i >> 5, u = i & 31;
        z0[r * 37 + u] = ((const uint4v*)(ht + (size_t)(tok0 + r) * 256))[u];
    }
    for (int i = tid; i < 64 * 5; i += 256) {
        int r = i / 5, u = 32 + (i % 5);
        uint4v v = {0u, 0u, 0u, 0u};
        if (u == 32) {
            const float* xp = x + (size_t)(tok0 + r) * 12 + 7;
            v.x = packf16(xp[0], xp[1]);
            v.y = packf16(xp[2], xp[3]);
            v.z = packf16(xp[4], 0.f);
        }
        z0[r * 37 + u] = v;
    }
    __syncthreads();

    mfma_layer<9, 16, false>(P.bf[0], P.bias[0], 256, z0, z1, w, lane, m15, q);
    __syncthreads();
    mfma_layer<8, 8, false>(P.bf[1], P.bias[1], 128, z1, z0, w, lane, m15, q);
    __syncthreads();
    mfma_layer<4, 4, false>(P.bf[2], P.bias[2], 64, z0, z1, w, lane, m15, q);
    __syncthreads();
    mfma_layer<2, 2, true>(P.bf[3], P.bias[3], 32, z1, z0, w, lane, m15, q);
    __syncthreads();
    mfma_layer<1, 1, true>(P.bf[4], P.bias[4], 16, z0, z1, w, lane, m15, q);
    __syncthreads();
    mfma_layer<1, 1, true>(P.bf[5], P.bias[5], 8, z1, z0, w, lane, m15, q);
    __syncthreads();

    // L6 head: K=8 (padded 32), N=7; no activation; fp32 out
    {
        f16x8 a = __builtin_bit_cast(f16x8, z0[(w * 16 + m15) * 37 + q]);
        f16x8 b = __builtin_bit_cast(f16x8, P.bf[6][lane]);
        f32x4 acc = (f32x4){0.f, 0.f, 0.f, 0.f};
        acc = __builtin_amdgcn_mfma_f32_16x16x32_f16(a, b, acc, 0, 0, 0);
        if (m15 < 7) {
            const float bv = P.bias[6][m15];
#pragma unroll
            for (int r = 0; r < 4; ++r)
                out[(size_t)(tok0 + w * 16 + q * 4 + r) * 7 + m15] = acc[r] + bv;
        }
    }
}

// ============ launch ============
extern "C" void kernel_launch(void* const* d_in, const int* in_sizes, int n_in,
                              void* d_out, int out_size, void* d_ws, size_t ws_size,
                              hipStream_t stream) {
    const float* x = (const float*)d_in[0];
    const float* Wih = (const float*)d_in[1];
    const float* Whh = (const float*)d_in[2];
    const float* bih = (const float*)d_in[3];
    const float* bhh = (const float*)d_in[4];
    const float* W[7];
    const float* bb[7];
    for (int j = 0; j < 7; ++j) {
        W[j] = (const float*)d_in[5 + 2 * j];
        bb[j] = (const float*)d_in[6 + 2 * j];
    }
    float* out = (float*)d_out;

    static const int Kd[7] = {261, 256, 128, 64, 32, 16, 8};
    static const int Nd[7] = {256, 128, 64, 32, 16, 8, 7};
    static const int KSd[7] = {9, 8, 4, 2, 1, 1, 1};
    static const int NTd[7] = {16, 8, 4, 2, 1, 1, 1};

    char* ws = (char*)d_ws;
    f16* ht = (f16*)ws;  // 128 MiB, plain [b][t][j]
    size_t off = (size_t)NTOK * HH * 2;
    uint* Wsw = (uint*)(ws + off);
    off += (size_t)256 * 128 * 4;
    uint4v* bfp[7];
    for (int j = 0; j < 7; ++j) {
        bfp[j] = (uint4v*)(ws + off);
        off += (size_t)NTd[j] * KSd[j] * 64 * 16;
    }

    rnn_wswz_kernel<<<128, 256, 0, stream>>>(Whh, Wsw);
    for (int j = 0; j < 7; ++j) {
        int cnt = NTd[j] * KSd[j] * 64;
        bfrag_prep_kernel<<<(cnt + 255) / 256, 256, 0, stream>>>(W[j], bfp[j], Nd[j], Kd[j],
                                                                 KSd[j], NTd[j]);
    }

    rnn_kernel<<<BB, 256, 0, stream>>>(x, Wsw, Wih, bih, bhh, ht, out + (size_t)NTOK * 7);

    MlpB P;
    for (int j = 0; j < 7; ++j) {
        P.bf[j] = bfp[j];
        P.bias[j] = bb[j];
    }
    mlp_kernel<<<NTOK / 64, 256, 0, stream>>>(ht, x, P, out);
}